// Round 1
// baseline (15923.439 us; speedup 1.0000x reference)
//
#include <hip/hip_runtime.h>

#define BB 128
#define TT 128
#define INF 171
#define HID 1024
#define G4 4096

typedef short short8 __attribute__((ext_vector_type(8)));
typedef float floatx4 __attribute__((ext_vector_type(4)));
typedef unsigned short u16;

__device__ __forceinline__ u16 f2b(float f){
  unsigned x = __builtin_bit_cast(unsigned, f);
  unsigned r = (x + 0x7FFFu + ((x>>16)&1u)) >> 16;
  return (u16)r;
}
__device__ __forceinline__ float b2f(u16 u){
  return __builtin_bit_cast(float, ((unsigned)u)<<16);
}
__device__ __forceinline__ float sigm(float x){ return 1.f/(1.f+__expf(-x)); }
__device__ __forceinline__ float tanh_(float x){ return 1.f - 2.f/(__expf(2.f*x)+1.f); }

// ---------------- weight prep ----------------
// W1cat: [4096][1280] = [Wih1(171) | Whh1(1024) | pad0(85)] split hi/lo bf16
__global__ __launch_bounds__(256) void prep_w1(const float* __restrict__ Wih1,
    const float* __restrict__ Whh1, u16* __restrict__ Wh, u16* __restrict__ Wl){
  size_t idx = (size_t)blockIdx.x*256 + threadIdx.x;   // grid exact: 4096*1280/256
  int r = (int)(idx / 1280), k = (int)(idx % 1280);
  float w = 0.f;
  if (k < 171)       w = Wih1[(size_t)r*171 + k];
  else if (k < 1195) w = Whh1[(size_t)r*1024 + (k-171)];
  u16 h = f2b(w); Wh[idx] = h; Wl[idx] = f2b(w - b2f(h));
}

// W2cat/W3cat: [4096][2048] = [Wih(1024) | Whh(1024)]
__global__ __launch_bounds__(256) void prep_w23(const float* __restrict__ Wih2,
    const float* __restrict__ Whh2, const float* __restrict__ Wih3,
    const float* __restrict__ Whh3, u16* __restrict__ W2h, u16* __restrict__ W2l,
    u16* __restrict__ W3h, u16* __restrict__ W3l){
  size_t idx = (size_t)blockIdx.x*256 + threadIdx.x;   // grid exact: 4096*2048/256
  int r = (int)(idx >> 11), k = (int)(idx & 2047);
  size_t si = (size_t)r*1024 + (k & 1023);
  float w2 = (k < 1024) ? Wih2[si] : Whh2[si];
  float w3 = (k < 1024) ? Wih3[si] : Whh3[si];
  u16 h2v = f2b(w2); W2h[idx] = h2v; W2l[idx] = f2b(w2 - b2f(h2v));
  u16 h3v = f2b(w3); W3h[idx] = h3v; W3l[idx] = f2b(w3 - b2f(h3v));
}

// Wdec [176][1024] (rows>=171 zero) + biases + state init + counters
__global__ __launch_bounds__(256) void prep_misc(const float* __restrict__ Wdec,
    const float* __restrict__ bdec_in,
    const float* __restrict__ bih1, const float* __restrict__ bhh1,
    const float* __restrict__ bih2, const float* __restrict__ bhh2,
    const float* __restrict__ bih3, const float* __restrict__ bhh3,
    const float* __restrict__ rseq, const int* __restrict__ gnp,
    u16* __restrict__ Wdh, u16* __restrict__ Wdl,
    float* __restrict__ b1, float* __restrict__ b2, float* __restrict__ b3,
    float* __restrict__ bd, u16* __restrict__ Xb1, u16* __restrict__ Hbuf,
    float* __restrict__ cbuf, int* __restrict__ cnts)
{
  size_t idx = (size_t)blockIdx.x*256 + threadIdx.x;
  if (idx < 180224){                     // Wdec 176*1024
    int r = (int)(idx>>10);
    float w = (r < 171) ? Wdec[idx - (size_t)(r-0)*0 - 0 + 0*0 + ( (size_t)r*1024 + (idx&1023) ) - idx + idx] : 0.f;
    // simpler: recompute
    int k = (int)(idx & 1023);
    w = (r < 171) ? Wdec[(size_t)r*1024 + k] : 0.f;
    u16 h = f2b(w); Wdh[idx] = h; Wdl[idx] = f2b(w - b2f(h));
    return;
  }
  idx -= 180224;
  if (idx < 12288){                      // b1|b2|b3 (4096 each)
    int which = (int)(idx >> 12), j = (int)(idx & 4095);
    float v = (which==0) ? (bih1[j]+bhh1[j]) : (which==1) ? (bih2[j]+bhh2[j]) : (bih3[j]+bhh3[j]);
    ((which==0)?b1:(which==1)?b2:b3)[j] = v;
    return;
  }
  idx -= 12288;
  if (idx < 176){ bd[idx] = (idx < 171) ? bdec_in[idx] : 0.f; return; }
  idx -= 176;
  if (idx < 327680){                     // Xb1 2 parities [q][b][1280]
    size_t q = idx / 163840; size_t rem = idx % 163840;
    int b = (int)(rem / 1280), k = (int)(rem % 1280);
    float v = 0.f;
    if (q==0 && k < 171 && *gnp > 0) v = rseq[(size_t)b*TT*INF + k];  // in_frame(0)
    Xb1[(size_t)blockIdx.x*0 + (q*163840 + rem)] = f2b(v);
    return;
  }
  idx -= 327680;
  if (idx < 786432){ Hbuf[idx] = 0; return; }     // H0/H1/H2 x 2 parities
  idx -= 786432;
  if (idx < 393216){ cbuf[idx] = 0.f; return; }   // c0,c1,c2
  idx -= 393216;
  if (idx < 128){ cnts[idx] = 0; }
}

// ---------------- fused LSTM layer GEMM (+last-block cell update) ----------------
// grid 256 = (js in [0,64)) * 4 + kq ; block 256 threads (4 waves, wave = 4 Mtiles x 2 Ntiles)
// computes gates[4096 x 128] partial over K-quarter, last block per js does the
// i,f,g,o -> c,h update for units js*16..+16 and writes h (bf16) to hdA/hdB.
template<int KTOT>
__global__ __launch_bounds__(256) void lstm_gemm(
    const u16* __restrict__ Wh, const u16* __restrict__ Wl,
    const u16* XA, const u16* XB, int xstr, int xsplit,
    float* __restrict__ part, int* cnt,
    const float* __restrict__ bias, float* cbuf,
    u16* hdA, int strA, u16* hdB, int strB)
{
  constexpr int KQ = KTOT/4;
  const int js = (int)blockIdx.x >> 2;
  const int kq = (int)blockIdx.x & 3;
  const int tid = threadIdx.x;
  const int w = tid >> 6, l = tid & 63;
  const int l15 = l & 15, lq = l >> 4;
  __shared__ u16 Abuf[128*128];   // 32KB : [2 terms * 4 tiles * 16 rows][klen<=128]
  __shared__ int lastflag;
  floatx4 acc[4][2];
  #pragma unroll
  for (int m=0;m<4;m++){ acc[m][0] = {0.f,0.f,0.f,0.f}; acc[m][1] = {0.f,0.f,0.f,0.f}; }
  const int k0base = kq*KQ;
  const u16* Xp; int krel;
  if (k0base >= xsplit){ Xp = XB; krel = k0base - xsplit; } else { Xp = XA; krel = k0base; }
  const u16* xrow = Xp + (size_t)(w*32 + l15)*xstr + krel + lq*8;

  for (int kc = 0; kc < KQ; kc += 128){
    const int klen = (KQ - kc >= 128) ? 128 : (KQ - kc);   // 128 or 64
    const int k8 = klen >> 3;
    const int sh = (klen == 128) ? 4 : 3;
    const int units = klen << 4;          // 2*64*k8
    for (int u = tid; u < units; u += 256){
      int row = u >> sh;
      int kk = (u & (k8-1)) << 3;
      int term = row >> 6, r6 = row & 63;
      int tile = r6 >> 4, rin = r6 & 15;
      const u16* src = (term ? Wl : Wh)
          + (size_t)(tile*1024 + js*16 + rin)*KTOT + (k0base + kc + kk);
      *(short8*)&Abuf[(size_t)row*klen + kk] = *(const short8*)src;
    }
    __syncthreads();
    for (int ks = 0; ks < klen; ks += 32){
      short8 b0 = *(const short8*)(xrow + kc + ks);
      short8 b1 = *(const short8*)(xrow + kc + ks + (size_t)16*xstr);
      #pragma unroll
      for (int mt=0; mt<4; mt++){
        short8 ah = *(const short8*)&Abuf[(size_t)(mt*16 + l15)*klen + ks + lq*8];
        short8 al = *(const short8*)&Abuf[(size_t)(64 + mt*16 + l15)*klen + ks + lq*8];
        acc[mt][0] = __builtin_amdgcn_mfma_f32_16x16x32_bf16(ah, b0, acc[mt][0], 0,0,0);
        acc[mt][1] = __builtin_amdgcn_mfma_f32_16x16x32_bf16(ah, b1, acc[mt][1], 0,0,0);
        acc[mt][0] = __builtin_amdgcn_mfma_f32_16x16x32_bf16(al, b0, acc[mt][0], 0,0,0);
        acc[mt][1] = __builtin_amdgcn_mfma_f32_16x16x32_bf16(al, b1, acc[mt][1], 0,0,0);
      }
    }
    __syncthreads();
  }
  // store partial gates: part[kq][4096][128]
  float* pb = part + (size_t)kq*G4*BB;
  #pragma unroll
  for (int mt=0; mt<4; mt++){
    int row0 = mt*1024 + js*16 + lq*4;
    #pragma unroll
    for (int nt=0; nt<2; nt++){
      int col = w*32 + nt*16 + l15;
      #pragma unroll
      for (int r=0;r<4;r++) pb[(size_t)(row0+r)*BB + col] = acc[mt][nt][r];
    }
  }
  __syncthreads();
  if (tid==0){
    __threadfence();                              // release our partials device-wide
    int old = atomicAdd(&cnt[js], 1);
    if (old == 3){ __threadfence(); lastflag = 1; }  // acquire: invalidate caches
    else lastflag = 0;
  }
  __syncthreads();
  if (!lastflag) return;
  // epilogue: units j = js*16..+16, batch 0..128
  for (int p = tid; p < 16*BB; p += 256){
    int u = p >> 7, b = p & 127;
    int j = js*16 + u;
    float gi = bias[j], gf = bias[1024+j], gg = bias[2048+j], go = bias[3072+j];
    #pragma unroll
    for (int q=0;q<4;q++){
      const float* pq = part + (size_t)q*G4*BB;
      gi += pq[(size_t)j*BB + b];
      gf += pq[(size_t)(1024+j)*BB + b];
      gg += pq[(size_t)(2048+j)*BB + b];
      go += pq[(size_t)(3072+j)*BB + b];
    }
    float ii = sigm(gi), ff = sigm(gf), g = tanh_(gg), oo = sigm(go);
    size_t ci = (size_t)j*BB + b;
    float c = ff*cbuf[ci] + ii*g;
    cbuf[ci] = c;
    float h = oo*tanh_(c);
    u16 hb = f2b(h);
    hdA[(size_t)b*strA + j] = hb;
    if (hdB) hdB[(size_t)b*strB + j] = hb;
  }
  if (tid==0) cnt[js] = 0;
}

// ---------------- decoder GEMM + output + next in_frame ----------------
// grid 44 = mt(11) * 4 + kq ; rows o = mt*16.. (padded to 176), K=1024 quartered
__global__ __launch_bounds__(256) void dec_gemm(
    const u16* __restrict__ Wh, const u16* __restrict__ Wl,
    const u16* __restrict__ X,
    float* __restrict__ part2, int* cnt2, const float* __restrict__ bias,
    const float* __restrict__ rseq, float* __restrict__ out,
    u16* xb1, const int* cnp, const int* gnp, int t)
{
  const int mt = (int)blockIdx.x >> 2;
  const int kq = (int)blockIdx.x & 3;
  const int tid = threadIdx.x;
  const int w = tid>>6, l = tid&63, l15 = l&15, lq = l>>4;
  __shared__ int lastflag;
  floatx4 acc[2]; acc[0] = {0.f,0.f,0.f,0.f}; acc[1] = {0.f,0.f,0.f,0.f};
  const u16* xrow = X + (size_t)(w*32+l15)*1024 + kq*256 + lq*8;
  const u16* wrh = Wh + (size_t)(mt*16+l15)*1024 + kq*256 + lq*8;
  const u16* wrl = Wl + (size_t)(mt*16+l15)*1024 + kq*256 + lq*8;
  #pragma unroll
  for (int ks=0; ks<256; ks+=32){
    short8 b0 = *(const short8*)(xrow + ks);
    short8 b1 = *(const short8*)(xrow + ks + 16*1024);
    short8 ah = *(const short8*)(wrh + ks);
    short8 al = *(const short8*)(wrl + ks);
    acc[0] = __builtin_amdgcn_mfma_f32_16x16x32_bf16(ah,b0,acc[0],0,0,0);
    acc[1] = __builtin_amdgcn_mfma_f32_16x16x32_bf16(ah,b1,acc[1],0,0,0);
    acc[0] = __builtin_amdgcn_mfma_f32_16x16x32_bf16(al,b0,acc[0],0,0,0);
    acc[1] = __builtin_amdgcn_mfma_f32_16x16x32_bf16(al,b1,acc[1],0,0,0);
  }
  float* pb = part2 + (size_t)kq*176*BB;
  #pragma unroll
  for (int nt=0;nt<2;nt++){
    int col = w*32+nt*16+l15;
    #pragma unroll
    for (int r=0;r<4;r++) pb[(size_t)(mt*16+lq*4+r)*BB + col] = acc[nt][r];
  }
  __syncthreads();
  if (tid==0){
    __threadfence();
    int old = atomicAdd(&cnt2[mt], 1);
    if (old == 3){ __threadfence(); lastflag = 1; } else lastflag = 0;
  }
  __syncthreads();
  if (!lastflag) return;
  int cn = *cnp, gn = *gnp; int P = cn + gn;
  int nf = 0;
  if (t+1 < TT) nf = (((t+1) % P) < gn) ? 1 : 0;
  for (int p=tid; p<16*BB; p+=256){
    int u = p>>7, b = p&127;
    int o = mt*16 + u;
    if (o >= 171) continue;
    float v = bias[o];
    #pragma unroll
    for (int q=0;q<4;q++) v += part2[((size_t)q*176 + o)*BB + b];
    out[((size_t)b*TT + t)*171 + o] = v;
    if (t+1 < TT){
      float src = nf ? rseq[((size_t)b*TT + (t+1))*171 + o] : v;
      xb1[(size_t)b*1280 + o] = f2b(src);
    }
  }
  if (tid==0) cnt2[mt] = 0;
}

// ---------------- host ----------------
extern "C" void kernel_launch(void* const* d_in, const int* in_sizes, int n_in,
                              void* d_out, int out_size, void* d_ws, size_t ws_size,
                              hipStream_t stream)
{
  const float* rseq = (const float*)d_in[0];
  const float* Wih1 = (const float*)d_in[1];
  const float* Whh1 = (const float*)d_in[2];
  const float* bih1 = (const float*)d_in[3];
  const float* bhh1 = (const float*)d_in[4];
  const float* Wih2 = (const float*)d_in[5];
  const float* Whh2 = (const float*)d_in[6];
  const float* bih2 = (const float*)d_in[7];
  const float* bhh2 = (const float*)d_in[8];
  const float* Wih3 = (const float*)d_in[9];
  const float* Whh3 = (const float*)d_in[10];
  const float* bih3 = (const float*)d_in[11];
  const float* bhh3 = (const float*)d_in[12];
  const float* Wdec = (const float*)d_in[13];
  const float* bdec = (const float*)d_in[14];
  const int* cn = (const int*)d_in[15];
  const int* gn = (const int*)d_in[16];
  float* out = (float*)d_out;

  char* p = (char*)d_ws;
  auto take = [&](size_t n){ void* r = (void*)p; p += (n + 255) & ~(size_t)255; return r; };
  u16* W1h = (u16*)take(4096UL*1280*2);
  u16* W1l = (u16*)take(4096UL*1280*2);
  u16* W2h = (u16*)take(4096UL*2048*2);
  u16* W2l = (u16*)take(4096UL*2048*2);
  u16* W3h = (u16*)take(4096UL*2048*2);
  u16* W3l = (u16*)take(4096UL*2048*2);
  u16* Wdh = (u16*)take(176UL*1024*2);
  u16* Wdl = (u16*)take(176UL*1024*2);
  u16* Xb1 = (u16*)take(2UL*128*1280*2);     // [parity][b][1280] : in_frame|h0|pad
  u16* Hbuf = (u16*)take(6UL*128*1024*2);    // H0[2] H1[2] H2[2], [b][1024] bf16
  float* cbuf = (float*)take(3UL*1024*128*4);
  float* part = (float*)take(4UL*4096*128*4);
  float* part2 = (float*)take(4UL*176*128*4);
  float* b1 = (float*)take(4096*4);
  float* b2 = (float*)take(4096*4);
  float* b3 = (float*)take(4096*4);
  float* bd = (float*)take(176*4);
  int* cnts = (int*)take(128*4);
  int* cnt2 = cnts + 64;
  if ((size_t)(p - (char*)d_ws) > ws_size) return;   // ws too small -> visible as stub-like absmax

  prep_w1 <<<20480,256,0,stream>>>(Wih1, Whh1, W1h, W1l);
  prep_w23<<<32768,256,0,stream>>>(Wih2, Whh2, Wih3, Whh3, W2h, W2l, W3h, W3l);
  prep_misc<<<6642,256,0,stream>>>(Wdec, bdec, bih1,bhh1,bih2,bhh2,bih3,bhh3,
      rseq, gn, Wdh, Wdl, b1,b2,b3,bd, Xb1, Hbuf, cbuf, cnts);

  const size_t XB1SZ = 128UL*1280;
  const size_t HSZ = 128UL*1024;
  u16* H0[2] = { Hbuf,           Hbuf + HSZ };
  u16* H1[2] = { Hbuf + 2*HSZ,   Hbuf + 3*HSZ };
  u16* H2[2] = { Hbuf + 4*HSZ,   Hbuf + 5*HSZ };
  float* c0 = cbuf;
  float* c1 = cbuf + 1024*128;
  float* c2 = cbuf + 2*1024*128;

  for (int t=0; t<TT; t++){
    int pr = t & 1, nx = pr ^ 1;
    // L1: x = [in_frame(t) | h0(t-1)] in Xb1[pr]; h0(t) -> H0[pr] and Xb1[nx]+171
    lstm_gemm<1280><<<256,256,0,stream>>>(W1h, W1l,
        Xb1 + pr*XB1SZ, Xb1 + pr*XB1SZ, 1280, (1<<28),
        part, cnts, b1, c0,
        H0[pr], 1024, Xb1 + nx*XB1SZ + 171, 1280);
    // L2: x = [h0(t) | h1(t-1)]; h1(t) -> H1[pr]
    lstm_gemm<2048><<<256,256,0,stream>>>(W2h, W2l,
        H0[pr], H1[nx], 1024, 1024,
        part, cnts, b2, c1,
        H1[pr], 1024, (u16*)nullptr, 0);
    // L3: x = [h1(t) | h2(t-1)]; h2(t) -> H2[pr]
    lstm_gemm<2048><<<256,256,0,stream>>>(W3h, W3l,
        H1[pr], H2[nx], 1024, 1024,
        part, cnts, b3, c2,
        H2[pr], 1024, (u16*)nullptr, 0);
    // dec: out[:,t,:] = h2(t) @ Wdec^T + bd ; write in_frame(t+1) into Xb1[nx]
    dec_gemm<<<44,256,0,stream>>>(Wdh, Wdl, H2[pr],
        part2, cnt2, bd, rseq, out, Xb1 + nx*XB1SZ, cn, gn, t);
  }
}

// Round 3
// 9719.646 us; speedup vs baseline: 1.6383x; 1.6383x over previous
//
#include <hip/hip_runtime.h>

#define TT 128
#define INF 171

typedef short short8 __attribute__((ext_vector_type(8)));
typedef float floatx4 __attribute__((ext_vector_type(4)));
typedef unsigned short u16;

__device__ __forceinline__ u16 f2b(float f){
  unsigned x = __builtin_bit_cast(unsigned, f);
  return (u16)((x + 0x7FFFu + ((x>>16)&1u)) >> 16);
}
__device__ __forceinline__ float b2f(u16 u){ return __builtin_bit_cast(float, ((unsigned)u)<<16); }
__device__ __forceinline__ float sigm(float x){ return 1.f/(1.f+__expf(-x)); }
__device__ __forceinline__ float tanh_(float x){ return 1.f - 2.f/(__expf(2.f*x)+1.f); }

// scatter one bf16 value into a fragment-ordered activation buffer
// layout: [btile][kchunk(nch)][lane(64)][8] ; lane = ((k>>3)&3)*16 + (b&15), elem = k&7
__device__ __forceinline__ void scat(u16* buf, int nch, int b, int k, u16 v){
  buf[ (size_t)((((b>>4)*nch + (k>>5))*4 + ((k>>3)&3))*16 + (b&15))*8 + (k&7) ] = v;
}

// ---------------- weight prep (fragment-swizzled, hi/lo split) ----------------
// W1f: [256 tiles][40 kc][2 terms][64 lanes][8] ; row = (tile>>6)*1024 + (tile&63)*16 + (l&15)
// k<171: Wih1 ; 171<=k<1195: Whh1 ; else 0
__global__ __launch_bounds__(256) void prep_w1f(const float* __restrict__ Wih1,
    const float* __restrict__ Whh1, u16* __restrict__ Wf){
  int u = blockIdx.x*256 + threadIdx.x;          // exactly 655360 units
  int tile = u / 2560;                            // 40*64
  int r = u - tile*2560;
  int kc = r >> 6, l = r & 63;
  int row = (tile>>6)*1024 + (tile&63)*16 + (l&15);
  int k0 = kc*32 + ((l>>4)<<3);
  short8 hi, lo;
  #pragma unroll
  for (int e=0;e<8;e++){
    int k = k0+e;
    float w = 0.f;
    if (k < 171)       w = Wih1[(size_t)row*171 + k];
    else if (k < 1195) w = Whh1[(size_t)row*1024 + (k-171)];
    u16 h = f2b(w);
    hi[e] = (short)h; lo[e] = (short)f2b(w - b2f(h));
  }
  size_t base = (size_t)(tile*40 + kc)*1024 + (size_t)l*8;
  *(short8*)&Wf[base] = hi;
  *(short8*)&Wf[base + 512] = lo;
}

// W2f/W3f: [256][64][2][64][8] ; k<1024: Wih ; else Whh
__global__ __launch_bounds__(256) void prep_w23f(const float* __restrict__ Wih2,
    const float* __restrict__ Whh2, const float* __restrict__ Wih3,
    const float* __restrict__ Whh3, u16* __restrict__ W2f, u16* __restrict__ W3f){
  int u = blockIdx.x*256 + threadIdx.x;          // exactly 1048576 units
  int tile = u >> 12;
  int r = u & 4095;
  int kc = r >> 6, l = r & 63;
  int row = (tile>>6)*1024 + (tile&63)*16 + (l&15);
  int k0 = kc*32 + ((l>>4)<<3);
  short8 h2, l2, h3, l3;
  #pragma unroll
  for (int e=0;e<8;e++){
    int k = k0+e;
    size_t si = (size_t)row*1024 + (k & 1023);
    float w2 = (k < 1024) ? Wih2[si] : Whh2[si];
    float w3 = (k < 1024) ? Wih3[si] : Whh3[si];
    u16 a = f2b(w2); h2[e] = (short)a; l2[e] = (short)f2b(w2 - b2f(a));
    u16 b = f2b(w3); h3[e] = (short)b; l3[e] = (short)f2b(w3 - b2f(b));
  }
  size_t base = (size_t)(tile*64 + kc)*1024 + (size_t)l*8;
  *(short8*)&W2f[base] = h2; *(short8*)&W2f[base+512] = l2;
  *(short8*)&W3f[base] = h3; *(short8*)&W3f[base+512] = l3;
}

// Wdf: [11][32][2][64][8] ; rows >=171 zero
__global__ __launch_bounds__(256) void prep_wdecf(const float* __restrict__ Wdec,
    u16* __restrict__ Wdf){
  int u = blockIdx.x*256 + threadIdx.x;          // exactly 22528 units
  int tile = u / 2048;                            // 32*64
  int r = u & 2047;
  int kc = r >> 6, l = r & 63;
  int row = tile*16 + (l&15);
  int k0 = kc*32 + ((l>>4)<<3);
  short8 hi, lo;
  #pragma unroll
  for (int e=0;e<8;e++){
    int k = k0+e;
    float w = (row < 171) ? Wdec[(size_t)row*1024 + k] : 0.f;
    u16 h = f2b(w);
    hi[e] = (short)h; lo[e] = (short)f2b(w - b2f(h));
  }
  size_t base = (size_t)(tile*32 + kc)*1024 + (size_t)l*8;
  *(short8*)&Wdf[base] = hi;
  *(short8*)&Wdf[base + 512] = lo;
}

// biases + activation-buffer init (+ step-0 frame) + c init
__global__ __launch_bounds__(256) void prep_misc(
    const float* __restrict__ rseq, const int* __restrict__ gnp,
    const float* __restrict__ bih1, const float* __restrict__ bhh1,
    const float* __restrict__ bih2, const float* __restrict__ bhh2,
    const float* __restrict__ bih3, const float* __restrict__ bhh3,
    const float* __restrict__ bdec,
    u16* __restrict__ Xb1f, u16* __restrict__ Hf, float* __restrict__ cbuf,
    float* __restrict__ b1, float* __restrict__ b2, float* __restrict__ b3,
    float* __restrict__ bd)
{
  size_t idx = (size_t)blockIdx.x*256 + threadIdx.x;
  if (idx < 327680){                       // Xb1f, 2 parities x [8][40][64][8]
    int q = (int)(idx / 163840);
    int rem = (int)(idx % 163840);
    int btile = rem / 20480;               // 40*64*8
    int r2 = rem % 20480;
    int kc = r2 >> 9, r3 = r2 & 511;
    int l = r3 >> 3, e = r3 & 7;
    int b = btile*16 + (l&15);
    int k = kc*32 + ((l>>4)<<3) + e;
    float v = 0.f;
    if (q==0 && k < 171 && *gnp > 0) v = rseq[(size_t)b*TT*INF + k];
    Xb1f[idx] = f2b(v);
    return;
  }
  idx -= 327680;
  if (idx < 786432){ Hf[idx] = 0; return; }        // H0/H1/H2 x 2 parities
  idx -= 786432;
  if (idx < 393216){ cbuf[idx] = 0.f; return; }    // c0,c1,c2
  idx -= 393216;
  if (idx < 12288){
    int which = (int)(idx >> 12), j = (int)(idx & 4095);
    float v = (which==0)? (bih1[j]+bhh1[j]) : (which==1)? (bih2[j]+bhh2[j]) : (bih3[j]+bhh3[j]);
    ((which==0)?b1:(which==1)?b2:b3)[j] = v;
    return;
  }
  idx -= 12288;
  if (idx < 176) bd[idx] = (idx < 171) ? bdec[idx] : 0.f;
}

// ---------------- LSTM layer: full-K per block, local epilogue ----------------
// 256 blocks = 64 js-groups x 4 batch-quarters, XCD-swizzled so the 4 siblings
// of a js-group share an XCD class (L2 weight reuse). 4 waves: wave g = gate g,
// M=16 units x N=32 batch, full K. Gate exchange via LDS; cell update local.
template<int NCA, int NCB>
__global__ __launch_bounds__(256) void lstm_f(
    const u16* __restrict__ Wf,
    const u16* __restrict__ XAf, const u16* __restrict__ XBf,
    const float* __restrict__ bias, float* __restrict__ cbuf,
    u16* __restrict__ hd0, int nch0, int koff0,
    u16* __restrict__ hd1, int nch1, int koff1)
{
  constexpr int NCH = NCA + NCB;
  const int bId = (int)blockIdx.x;
  const int js = (bId & 7)*8 + ((bId >> 5) & 7);   // same (bId&7) => same XCD class
  const int nq = (bId >> 3) & 3;
  const int tid = (int)threadIdx.x;
  const int g = tid >> 6, l = tid & 63;
  const int l15 = l & 15, lq = l >> 4;

  const u16* wp  = Wf  + (size_t)(g*64 + js)*NCH*1024 + (size_t)(l<<3);
  const u16* xa0 = XAf + (size_t)(nq*2    )*NCA*512  + (size_t)(l<<3);
  const u16* xa1 = XAf + (size_t)(nq*2 + 1)*NCA*512  + (size_t)(l<<3);

  floatx4 ah0{}, ah1{}, al0{}, al1{};
  #pragma unroll 8
  for (int kc=0; kc<NCA; kc++){
    short8 wh  = *(const short8*)(wp  + (size_t)kc*1024);
    short8 wl  = *(const short8*)(wp  + (size_t)kc*1024 + 512);
    short8 xb0 = *(const short8*)(xa0 + (size_t)kc*512);
    short8 xb1 = *(const short8*)(xa1 + (size_t)kc*512);
    ah0 = __builtin_amdgcn_mfma_f32_16x16x32_bf16(wh, xb0, ah0, 0,0,0);
    ah1 = __builtin_amdgcn_mfma_f32_16x16x32_bf16(wh, xb1, ah1, 0,0,0);
    al0 = __builtin_amdgcn_mfma_f32_16x16x32_bf16(wl, xb0, al0, 0,0,0);
    al1 = __builtin_amdgcn_mfma_f32_16x16x32_bf16(wl, xb1, al1, 0,0,0);
  }
  if constexpr (NCB > 0){
    const u16* wp2 = wp + (size_t)NCA*1024;
    const u16* xc0 = XBf + (size_t)(nq*2    )*NCB*512 + (size_t)(l<<3);
    const u16* xc1 = XBf + (size_t)(nq*2 + 1)*NCB*512 + (size_t)(l<<3);
    #pragma unroll 8
    for (int kc=0; kc<NCB; kc++){
      short8 wh  = *(const short8*)(wp2 + (size_t)kc*1024);
      short8 wl  = *(const short8*)(wp2 + (size_t)kc*1024 + 512);
      short8 xb0 = *(const short8*)(xc0 + (size_t)kc*512);
      short8 xb1 = *(const short8*)(xc1 + (size_t)kc*512);
      ah0 = __builtin_amdgcn_mfma_f32_16x16x32_bf16(wh, xb0, ah0, 0,0,0);
      ah1 = __builtin_amdgcn_mfma_f32_16x16x32_bf16(wh, xb1, ah1, 0,0,0);
      al0 = __builtin_amdgcn_mfma_f32_16x16x32_bf16(wl, xb0, al0, 0,0,0);
      al1 = __builtin_amdgcn_mfma_f32_16x16x32_bf16(wl, xb1, al1, 0,0,0);
    }
  }
  floatx4 a0 = ah0 + al0, a1 = ah1 + al1;

  __shared__ float gbuf[4][16][33];    // +1 pad breaks 4-way bank aliasing
  #pragma unroll
  for (int r=0;r<4;r++){
    gbuf[g][lq*4+r][l15]      = a0[r];
    gbuf[g][lq*4+r][16 + l15] = a1[r];
  }
  __syncthreads();

  #pragma unroll
  for (int rep=0; rep<2; rep++){
    int p = tid + rep*256;
    int uu = p >> 5, bq = p & 31;
    int j = js*16 + uu, bg = nq*32 + bq;
    float gi = gbuf[0][uu][bq] + bias[j];
    float gf = gbuf[1][uu][bq] + bias[1024 + j];
    float gg = gbuf[2][uu][bq] + bias[2048 + j];
    float go = gbuf[3][uu][bq] + bias[3072 + j];
    size_t ci = (size_t)j*128 + bg;
    float c = sigm(gf)*cbuf[ci] + sigm(gi)*tanh_(gg);
    cbuf[ci] = c;
    u16 hb = f2b(sigm(go)*tanh_(c));
    scat(hd0, nch0, bg, koff0 + j, hb);
    if (nch1) scat(hd1, nch1, bg, koff1 + j, hb);
  }
}

// ---------------- decoder: 11 blocks, wave = batch-quarter, local epilogue ----
__global__ __launch_bounds__(256) void dec_f(
    const u16* __restrict__ Wdf, const u16* __restrict__ Xf,
    const float* __restrict__ bd, const float* __restrict__ rseq,
    float* __restrict__ out, u16* __restrict__ xnext,
    const int* __restrict__ cnp, const int* __restrict__ gnp, int t)
{
  const int tile = (int)blockIdx.x;     // 0..10, rows o = tile*16..
  const int tid = (int)threadIdx.x;
  const int w = tid >> 6, l = tid & 63;
  const int l15 = l & 15, lq = l >> 4;
  const u16* wp = Wdf + (size_t)tile*32*1024 + (size_t)(l<<3);
  const u16* x0 = Xf + (size_t)(w*2    )*32*512 + (size_t)(l<<3);
  const u16* x1 = Xf + (size_t)(w*2 + 1)*32*512 + (size_t)(l<<3);
  floatx4 ah0{}, ah1{}, al0{}, al1{};
  #pragma unroll 8
  for (int kc=0; kc<32; kc++){
    short8 wh = *(const short8*)(wp + (size_t)kc*1024);
    short8 wl = *(const short8*)(wp + (size_t)kc*1024 + 512);
    short8 b0 = *(const short8*)(x0 + (size_t)kc*512);
    short8 b1 = *(const short8*)(x1 + (size_t)kc*512);
    ah0 = __builtin_amdgcn_mfma_f32_16x16x32_bf16(wh, b0, ah0, 0,0,0);
    ah1 = __builtin_amdgcn_mfma_f32_16x16x32_bf16(wh, b1, ah1, 0,0,0);
    al0 = __builtin_amdgcn_mfma_f32_16x16x32_bf16(wl, b0, al0, 0,0,0);
    al1 = __builtin_amdgcn_mfma_f32_16x16x32_bf16(wl, b1, al1, 0,0,0);
  }
  floatx4 a0 = ah0 + al0, a1 = ah1 + al1;
  int gn = *gnp;
  int P = *cnp + gn; if (P < 1) P = 1;
  int nf = (((t+1) % P) < gn) ? 1 : 0;
  #pragma unroll
  for (int r=0;r<4;r++){
    int o = tile*16 + lq*4 + r;
    if (o < 171){
      {
        int b = w*32 + l15;
        float v = a0[r] + bd[o];
        out[((size_t)b*TT + t)*INF + o] = v;
        if (t+1 < TT){
          float src = nf ? rseq[((size_t)b*TT + (t+1))*INF + o] : v;
          scat(xnext, 40, b, o, f2b(src));
        }
      }
      {
        int b = w*32 + 16 + l15;
        float v = a1[r] + bd[o];
        out[((size_t)b*TT + t)*INF + o] = v;
        if (t+1 < TT){
          float src = nf ? rseq[((size_t)b*TT + (t+1))*INF + o] : v;
          scat(xnext, 40, b, o, f2b(src));
        }
      }
    }
  }
}

// ---------------- host ----------------
extern "C" void kernel_launch(void* const* d_in, const int* in_sizes, int n_in,
                              void* d_out, int out_size, void* d_ws, size_t ws_size,
                              hipStream_t stream)
{
  const float* rseq = (const float*)d_in[0];
  const float* Wih1 = (const float*)d_in[1];
  const float* Whh1 = (const float*)d_in[2];
  const float* bih1 = (const float*)d_in[3];
  const float* bhh1 = (const float*)d_in[4];
  const float* Wih2 = (const float*)d_in[5];
  const float* Whh2 = (const float*)d_in[6];
  const float* bih2 = (const float*)d_in[7];
  const float* bhh2 = (const float*)d_in[8];
  const float* Wih3 = (const float*)d_in[9];
  const float* Whh3 = (const float*)d_in[10];
  const float* bih3 = (const float*)d_in[11];
  const float* bhh3 = (const float*)d_in[12];
  const float* Wdec = (const float*)d_in[13];
  const float* bdec = (const float*)d_in[14];
  const int* cn = (const int*)d_in[15];
  const int* gn = (const int*)d_in[16];
  float* out = (float*)d_out;

  char* p = (char*)d_ws;
  auto take = [&](size_t n){ void* r = (void*)p; p += (n + 255) & ~(size_t)255; return r; };
  u16* W1f  = (u16*)take(10485760UL*2);     // 256*40*2*64*8 elements  (FIX: was half)
  u16* W2f  = (u16*)take(16777216UL*2);     // 256*64*2*64*8
  u16* W3f  = (u16*)take(16777216UL*2);
  u16* Wdf  = (u16*)take(360448UL*2);       // 11*32*2*64*8
  u16* Xb1f = (u16*)take(327680UL*2);       // 2 parities x [8][40][512]
  u16* Hf   = (u16*)take(786432UL*2);       // 6 x [8][32][512]
  float* cbuf = (float*)take(393216UL*4);   // c0,c1,c2 [1024][128]
  float* b1 = (float*)take(4096*4);
  float* b2 = (float*)take(4096*4);
  float* b3 = (float*)take(4096*4);
  float* bd = (float*)take(176*4);
  if ((size_t)(p - (char*)d_ws) > ws_size) return;

  prep_w1f  <<<2560,256,0,stream>>>(Wih1, Whh1, W1f);
  prep_w23f <<<4096,256,0,stream>>>(Wih2, Whh2, Wih3, Whh3, W2f, W3f);
  prep_wdecf<<<88,  256,0,stream>>>(Wdec, Wdf);
  prep_misc <<<5937,256,0,stream>>>(rseq, gn, bih1,bhh1,bih2,bhh2,bih3,bhh3,bdec,
                                    Xb1f, Hf, cbuf, b1,b2,b3,bd);

  const size_t XBSZ = 163840;  // 8*40*512
  const size_t HSZ  = 131072;  // 8*32*512
  u16* H0f[2] = { Hf,          Hf + HSZ   };
  u16* H1f[2] = { Hf + 2*HSZ,  Hf + 3*HSZ };
  u16* H2f[2] = { Hf + 4*HSZ,  Hf + 5*HSZ };
  float* c0 = cbuf;
  float* c1 = cbuf + 131072;
  float* c2 = cbuf + 262144;

  for (int t=0; t<TT; t++){
    int pr = t & 1, nx = pr ^ 1;
    // L1: x = [frame|h0(t-1)] (fragment layout, 40 chunks); h0 -> H0f[pr] and Xb1f[nx]@171
    lstm_f<40,0><<<256,256,0,stream>>>(W1f, Xb1f + pr*XBSZ, (const u16*)nullptr,
        b1, c0, H0f[pr], 32, 0, Xb1f + nx*XBSZ, 40, 171);
    // L2: x = [h0(t) | h1(t-1)]
    lstm_f<32,32><<<256,256,0,stream>>>(W2f, H0f[pr], H1f[nx],
        b2, c1, H1f[pr], 32, 0, (u16*)nullptr, 0, 0);
    // L3: x = [h1(t) | h2(t-1)]
    lstm_f<32,32><<<256,256,0,stream>>>(W3f, H1f[pr], H2f[nx],
        b3, c2, H2f[pr], 32, 0, (u16*)nullptr, 0, 0);
    // dec: out[:,t,:] + next frame into Xb1f[nx]
    dec_f<<<11,256,0,stream>>>(Wdf, H2f[pr], bd, rseq, out, Xb1f + nx*XBSZ, cn, gn, t);
  }
}

// Round 4
// 9418.494 us; speedup vs baseline: 1.6907x; 1.0320x over previous
//
#include <hip/hip_runtime.h>

#define TT 128
#define INF 171

typedef short short8 __attribute__((ext_vector_type(8)));
typedef float floatx4 __attribute__((ext_vector_type(4)));
typedef unsigned short u16;
typedef unsigned int u32;

__device__ __forceinline__ u16 f2b(float f){
  unsigned x = __builtin_bit_cast(unsigned, f);
  return (u16)((x + 0x7FFFu + ((x>>16)&1u)) >> 16);
}
__device__ __forceinline__ float b2f(u16 u){ return __builtin_bit_cast(float, ((unsigned)u)<<16); }
__device__ __forceinline__ float sigm(float x){ return 1.f/(1.f+__expf(-x)); }
__device__ __forceinline__ float tanh_(float x){ return 1.f - 2.f/(__expf(2.f*x)+1.f); }

// async global->LDS, 16B per lane: lane l of the wave pulls g+16*l into ldsbase+16*l
__device__ __forceinline__ void gl_lds16(const u16* g, u16* l){
  __builtin_amdgcn_global_load_lds(
      reinterpret_cast<const __attribute__((address_space(1))) u32*>(
          reinterpret_cast<uintptr_t>(g)),
      reinterpret_cast<__attribute__((address_space(3))) u32*>(
          reinterpret_cast<uintptr_t>(l)),
      16, 0, 0);
}

__device__ __forceinline__ const u16* actp(const u16* xa, const u16* xb, int kcg, int nca){
  return (kcg < nca) ? xa + (size_t)kcg*512 : xb + (size_t)(kcg - nca)*512;
}

// scatter one bf16 value into a fragment-ordered activation buffer
// layout: [btile][kchunk(nch)][lane(64)][8] ; lane = ((k>>3)&3)*16 + (b&15), elem = k&7
__device__ __forceinline__ void scat(u16* buf, int nch, int b, int k, u16 v){
  buf[ (size_t)((((b>>4)*nch + (k>>5))*4 + ((k>>3)&3))*16 + (b&15))*8 + (k&7) ] = v;
}

// ---------------- weight prep (fragment-swizzled, hi/lo split) ----------------
// W1f: [256 tiles][40 kc][2 terms][64 lanes][8] ; row = (tile>>6)*1024 + (tile&63)*16 + (l&15)
__global__ __launch_bounds__(256) void prep_w1f(const float* __restrict__ Wih1,
    const float* __restrict__ Whh1, u16* __restrict__ Wf){
  int u = blockIdx.x*256 + threadIdx.x;          // exactly 655360 units
  int tile = u / 2560;                            // 40*64
  int r = u - tile*2560;
  int kc = r >> 6, l = r & 63;
  int row = (tile>>6)*1024 + (tile&63)*16 + (l&15);
  int k0 = kc*32 + ((l>>4)<<3);
  short8 hi, lo;
  #pragma unroll
  for (int e=0;e<8;e++){
    int k = k0+e;
    float w = 0.f;
    if (k < 171)       w = Wih1[(size_t)row*171 + k];
    else if (k < 1195) w = Whh1[(size_t)row*1024 + (k-171)];
    u16 h = f2b(w);
    hi[e] = (short)h; lo[e] = (short)f2b(w - b2f(h));
  }
  size_t base = (size_t)(tile*40 + kc)*1024 + (size_t)l*8;
  *(short8*)&Wf[base] = hi;
  *(short8*)&Wf[base + 512] = lo;
}

// W2f/W3f: [256][64][2][64][8] ; k<1024: Wih ; else Whh
__global__ __launch_bounds__(256) void prep_w23f(const float* __restrict__ Wih2,
    const float* __restrict__ Whh2, const float* __restrict__ Wih3,
    const float* __restrict__ Whh3, u16* __restrict__ W2f, u16* __restrict__ W3f){
  int u = blockIdx.x*256 + threadIdx.x;          // exactly 1048576 units
  int tile = u >> 12;
  int r = u & 4095;
  int kc = r >> 6, l = r & 63;
  int row = (tile>>6)*1024 + (tile&63)*16 + (l&15);
  int k0 = kc*32 + ((l>>4)<<3);
  short8 h2, l2, h3, l3;
  #pragma unroll
  for (int e=0;e<8;e++){
    int k = k0+e;
    size_t si = (size_t)row*1024 + (k & 1023);
    float w2 = (k < 1024) ? Wih2[si] : Whh2[si];
    float w3 = (k < 1024) ? Wih3[si] : Whh3[si];
    u16 a = f2b(w2); h2[e] = (short)a; l2[e] = (short)f2b(w2 - b2f(a));
    u16 b = f2b(w3); h3[e] = (short)b; l3[e] = (short)f2b(w3 - b2f(b));
  }
  size_t base = (size_t)(tile*64 + kc)*1024 + (size_t)l*8;
  *(short8*)&W2f[base] = h2; *(short8*)&W2f[base+512] = l2;
  *(short8*)&W3f[base] = h3; *(short8*)&W3f[base+512] = l3;
}

// Wdf: [11][32][2][64][8] ; rows >=171 zero
__global__ __launch_bounds__(256) void prep_wdecf(const float* __restrict__ Wdec,
    u16* __restrict__ Wdf){
  int u = blockIdx.x*256 + threadIdx.x;          // exactly 22528 units
  int tile = u / 2048;                            // 32*64
  int r = u & 2047;
  int kc = r >> 6, l = r & 63;
  int row = tile*16 + (l&15);
  int k0 = kc*32 + ((l>>4)<<3);
  short8 hi, lo;
  #pragma unroll
  for (int e=0;e<8;e++){
    int k = k0+e;
    float w = (row < 171) ? Wdec[(size_t)row*1024 + k] : 0.f;
    u16 h = f2b(w);
    hi[e] = (short)h; lo[e] = (short)f2b(w - b2f(h));
  }
  size_t base = (size_t)(tile*32 + kc)*1024 + (size_t)l*8;
  *(short8*)&Wdf[base] = hi;
  *(short8*)&Wdf[base + 512] = lo;
}

// biases + activation-buffer init (+ step-0 frame) + c init
__global__ __launch_bounds__(256) void prep_misc(
    const float* __restrict__ rseq, const int* __restrict__ gnp,
    const float* __restrict__ bih1, const float* __restrict__ bhh1,
    const float* __restrict__ bih2, const float* __restrict__ bhh2,
    const float* __restrict__ bih3, const float* __restrict__ bhh3,
    const float* __restrict__ bdec,
    u16* __restrict__ Xb1f, u16* __restrict__ Hf, float* __restrict__ cbuf,
    float* __restrict__ b1, float* __restrict__ b2, float* __restrict__ b3,
    float* __restrict__ bd)
{
  size_t idx = (size_t)blockIdx.x*256 + threadIdx.x;
  if (idx < 327680){                       // Xb1f, 2 parities x [8][40][64][8]
    int q = (int)(idx / 163840);
    int rem = (int)(idx % 163840);
    int btile = rem / 20480;               // 40*64*8
    int r2 = rem % 20480;
    int kc = r2 >> 9, r3 = r2 & 511;
    int l = r3 >> 3, e = r3 & 7;
    int b = btile*16 + (l&15);
    int k = kc*32 + ((l>>4)<<3) + e;
    float v = 0.f;
    if (q==0 && k < 171 && *gnp > 0) v = rseq[(size_t)b*TT*INF + k];
    Xb1f[idx] = f2b(v);
    return;
  }
  idx -= 327680;
  if (idx < 786432){ Hf[idx] = 0; return; }        // H0/H1/H2 x 2 parities
  idx -= 786432;
  if (idx < 393216){ cbuf[idx] = 0.f; return; }    // c0,c1,c2
  idx -= 393216;
  if (idx < 12288){
    int which = (int)(idx >> 12), j = (int)(idx & 4095);
    float v = (which==0)? (bih1[j]+bhh1[j]) : (which==1)? (bih2[j]+bhh2[j]) : (bih3[j]+bhh3[j]);
    ((which==0)?b1:(which==1)?b2:b3)[j] = v;
    return;
  }
  idx -= 12288;
  if (idx < 176) bd[idx] = (idx < 171) ? bdec[idx] : 0.f;
}

// ---------------- LSTM layer: global_load_lds double-buffered weight stream --
// 256 blocks = 64 js-groups x 4 batch-quarters (XCD-swizzled: 4 siblings co-XCD).
// 4 waves: wave g = gate g, M=16 units x N=32 batch, full K. Weights staged
// async into LDS in 8KB chunks (4 kc), ping-pong; acts prefetched into regs.
template<int NCA, int NCB>
__global__ __launch_bounds__(256) void lstm_f(
    const u16* __restrict__ Wf,
    const u16* __restrict__ XAf, const u16* __restrict__ XBf,
    const float* __restrict__ bias, float* __restrict__ cbuf,
    u16* __restrict__ hd0, int nch0, int koff0,
    u16* __restrict__ hd1, int nch1, int koff1)
{
  constexpr int NCH = NCA + NCB;
  constexpr int NCHUNK = NCH/4;
  __shared__ union SMU { u16 w[2][4][4][1024]; float gb[4][16][33]; } sm;  // 64 KB
  const int bId = (int)blockIdx.x;
  const int js = (bId & 7)*8 + ((bId >> 5) & 7);   // same (bId&7) => same XCD class
  const int nq = (bId >> 3) & 3;
  const int tid = (int)threadIdx.x;
  const int g = tid >> 6, l = tid & 63;
  const int l15 = l & 15, lq = l >> 4;

  const u16* wp  = Wf  + (size_t)(g*64 + js)*NCH*1024 + (size_t)(l<<3);
  const u16* xa0 = XAf + (size_t)(nq*2    )*NCA*512  + (size_t)(l<<3);
  const u16* xa1 = XAf + (size_t)(nq*2 + 1)*NCA*512  + (size_t)(l<<3);
  const u16* xb0 = (NCB>0) ? XBf + (size_t)(nq*2    )*NCB*512 + (size_t)(l<<3) : xa0;
  const u16* xb1 = (NCB>0) ? XBf + (size_t)(nq*2 + 1)*NCB*512 + (size_t)(l<<3) : xa1;

  floatx4 ah0{}, ah1{}, al0{}, al1{};
  short8 A0[4], A1[4], B0[4], B1[4];

  // prologue: stage chunk 0 (async), load acts chunk 0
  #pragma unroll
  for (int k2=0;k2<4;k2++){
    gl_lds16(wp + k2*1024,       &sm.w[0][g][k2][0]);
    gl_lds16(wp + k2*1024 + 512, &sm.w[0][g][k2][512]);
  }
  #pragma unroll
  for (int k2=0;k2<4;k2++){
    A0[k2] = *(const short8*)actp(xa0, xb0, k2, NCA);
    A1[k2] = *(const short8*)actp(xa1, xb1, k2, NCA);
  }
  __syncthreads();   // drains chunk-0 staging

  for (int c=0; c<NCHUNK; c++){
    const int st = c & 1;
    if (c+1 < NCHUNK){
      const u16* src = wp + (size_t)((c+1)*4)*1024;
      #pragma unroll
      for (int k2=0;k2<4;k2++){
        gl_lds16(src + k2*1024,       &sm.w[st^1][g][k2][0]);
        gl_lds16(src + k2*1024 + 512, &sm.w[st^1][g][k2][512]);
      }
      #pragma unroll
      for (int k2=0;k2<4;k2++){
        int kcg = (c+1)*4 + k2;
        B0[k2] = *(const short8*)actp(xa0, xb0, kcg, NCA);
        B1[k2] = *(const short8*)actp(xa1, xb1, kcg, NCA);
      }
    }
    // consume chunk c (staging of c+1 in flight)
    #pragma unroll
    for (int k2=0;k2<4;k2++){
      short8 wh = *(const short8*)&sm.w[st][g][k2][(l<<3)];
      short8 wl = *(const short8*)&sm.w[st][g][k2][512 + (l<<3)];
      ah0 = __builtin_amdgcn_mfma_f32_16x16x32_bf16(wh, A0[k2], ah0, 0,0,0);
      ah1 = __builtin_amdgcn_mfma_f32_16x16x32_bf16(wh, A1[k2], ah1, 0,0,0);
      al0 = __builtin_amdgcn_mfma_f32_16x16x32_bf16(wl, A0[k2], al0, 0,0,0);
      al1 = __builtin_amdgcn_mfma_f32_16x16x32_bf16(wl, A1[k2], al1, 0,0,0);
    }
    __syncthreads();   // drains staging of c+1, protects LDS reuse
    if (c+1 < NCHUNK){
      #pragma unroll
      for (int k2=0;k2<4;k2++){ A0[k2]=B0[k2]; A1[k2]=B1[k2]; }
    }
  }

  floatx4 a0 = ah0 + al0, a1 = ah1 + al1;
  // LDS safe to reuse: all waves passed the loop's final barrier
  #pragma unroll
  for (int r=0;r<4;r++){
    sm.gb[g][lq*4+r][l15]      = a0[r];
    sm.gb[g][lq*4+r][16 + l15] = a1[r];
  }
  __syncthreads();

  #pragma unroll
  for (int rep=0; rep<2; rep++){
    int p = tid + rep*256;
    int uu = p >> 5, bq = p & 31;
    int j = js*16 + uu, bg = nq*32 + bq;
    float gi = sm.gb[0][uu][bq] + bias[j];
    float gf = sm.gb[1][uu][bq] + bias[1024 + j];
    float gg = sm.gb[2][uu][bq] + bias[2048 + j];
    float go = sm.gb[3][uu][bq] + bias[3072 + j];
    size_t ci = (size_t)j*128 + bg;
    float c = sigm(gf)*cbuf[ci] + sigm(gi)*tanh_(gg);
    cbuf[ci] = c;
    u16 hb = f2b(sigm(go)*tanh_(c));
    scat(hd0, nch0, bg, koff0 + j, hb);
    if (nch1) scat(hd1, nch1, bg, koff1 + j, hb);
  }
}

// ---------------- decoder: 11 blocks, wave = batch-quarter, local epilogue ----
__global__ __launch_bounds__(256) void dec_f(
    const u16* __restrict__ Wdf, const u16* __restrict__ Xf,
    const float* __restrict__ bd, const float* __restrict__ rseq,
    float* __restrict__ out, u16* __restrict__ xnext,
    const int* __restrict__ cnp, const int* __restrict__ gnp, int t)
{
  const int tile = (int)blockIdx.x;     // 0..10, rows o = tile*16..
  const int tid = (int)threadIdx.x;
  const int w = tid >> 6, l = tid & 63;
  const int l15 = l & 15, lq = l >> 4;
  const u16* wp = Wdf + (size_t)tile*32*1024 + (size_t)(l<<3);
  const u16* x0 = Xf + (size_t)(w*2    )*32*512 + (size_t)(l<<3);
  const u16* x1 = Xf + (size_t)(w*2 + 1)*32*512 + (size_t)(l<<3);
  floatx4 ah0{}, ah1{}, al0{}, al1{};
  #pragma unroll 8
  for (int kc=0; kc<32; kc++){
    short8 wh = *(const short8*)(wp + (size_t)kc*1024);
    short8 wl = *(const short8*)(wp + (size_t)kc*1024 + 512);
    short8 b0 = *(const short8*)(x0 + (size_t)kc*512);
    short8 b1 = *(const short8*)(x1 + (size_t)kc*512);
    ah0 = __builtin_amdgcn_mfma_f32_16x16x32_bf16(wh, b0, ah0, 0,0,0);
    ah1 = __builtin_amdgcn_mfma_f32_16x16x32_bf16(wh, b1, ah1, 0,0,0);
    al0 = __builtin_amdgcn_mfma_f32_16x16x32_bf16(wl, b0, al0, 0,0,0);
    al1 = __builtin_amdgcn_mfma_f32_16x16x32_bf16(wl, b1, al1, 0,0,0);
  }
  floatx4 a0 = ah0 + al0, a1 = ah1 + al1;
  int gn = *gnp;
  int P = *cnp + gn; if (P < 1) P = 1;
  int nf = (((t+1) % P) < gn) ? 1 : 0;
  #pragma unroll
  for (int r=0;r<4;r++){
    int o = tile*16 + lq*4 + r;
    if (o < 171){
      {
        int b = w*32 + l15;
        float v = a0[r] + bd[o];
        out[((size_t)b*TT + t)*INF + o] = v;
        if (t+1 < TT){
          float src = nf ? rseq[((size_t)b*TT + (t+1))*INF + o] : v;
          scat(xnext, 40, b, o, f2b(src));
        }
      }
      {
        int b = w*32 + 16 + l15;
        float v = a1[r] + bd[o];
        out[((size_t)b*TT + t)*INF + o] = v;
        if (t+1 < TT){
          float src = nf ? rseq[((size_t)b*TT + (t+1))*INF + o] : v;
          scat(xnext, 40, b, o, f2b(src));
        }
      }
    }
  }
}

// ---------------- host ----------------
extern "C" void kernel_launch(void* const* d_in, const int* in_sizes, int n_in,
                              void* d_out, int out_size, void* d_ws, size_t ws_size,
                              hipStream_t stream)
{
  const float* rseq = (const float*)d_in[0];
  const float* Wih1 = (const float*)d_in[1];
  const float* Whh1 = (const float*)d_in[2];
  const float* bih1 = (const float*)d_in[3];
  const float* bhh1 = (const float*)d_in[4];
  const float* Wih2 = (const float*)d_in[5];
  const float* Whh2 = (const float*)d_in[6];
  const float* bih2 = (const float*)d_in[7];
  const float* bhh2 = (const float*)d_in[8];
  const float* Wih3 = (const float*)d_in[9];
  const float* Whh3 = (const float*)d_in[10];
  const float* bih3 = (const float*)d_in[11];
  const float* bhh3 = (const float*)d_in[12];
  const float* Wdec = (const float*)d_in[13];
  const float* bdec = (const float*)d_in[14];
  const int* cn = (const int*)d_in[15];
  const int* gn = (const int*)d_in[16];
  float* out = (float*)d_out;

  char* p = (char*)d_ws;
  auto take = [&](size_t n){ void* r = (void*)p; p += (n + 255) & ~(size_t)255; return r; };
  u16* W1f  = (u16*)take(10485760UL*2);     // 256*40*2*64*8 elements
  u16* W2f  = (u16*)take(16777216UL*2);     // 256*64*2*64*8
  u16* W3f  = (u16*)take(16777216UL*2);
  u16* Wdf  = (u16*)take(360448UL*2);       // 11*32*2*64*8
  u16* Xb1f = (u16*)take(327680UL*2);       // 2 parities x [8][40][512]
  u16* Hf   = (u16*)take(786432UL*2);       // 6 x [8][32][512]
  float* cbuf = (float*)take(393216UL*4);   // c0,c1,c2 [1024][128]
  float* b1 = (float*)take(4096*4);
  float* b2 = (float*)take(4096*4);
  float* b3 = (float*)take(4096*4);
  float* bd = (float*)take(176*4);
  if ((size_t)(p - (char*)d_ws) > ws_size) return;

  prep_w1f  <<<2560,256,0,stream>>>(Wih1, Whh1, W1f);
  prep_w23f <<<4096,256,0,stream>>>(Wih2, Whh2, Wih3, Whh3, W2f, W3f);
  prep_wdecf<<<88,  256,0,stream>>>(Wdec, Wdf);
  prep_misc <<<5937,256,0,stream>>>(rseq, gn, bih1,bhh1,bih2,bhh2,bih3,bhh3,bdec,
                                    Xb1f, Hf, cbuf, b1,b2,b3,bd);

  const size_t XBSZ = 163840;  // 8*40*512
  const size_t HSZ  = 131072;  // 8*32*512
  u16* H0f[2] = { Hf,          Hf + HSZ   };
  u16* H1f[2] = { Hf + 2*HSZ,  Hf + 3*HSZ };
  u16* H2f[2] = { Hf + 4*HSZ,  Hf + 5*HSZ };
  float* c0 = cbuf;
  float* c1 = cbuf + 131072;
  float* c2 = cbuf + 262144;

  for (int t=0; t<TT; t++){
    int pr = t & 1, nx = pr ^ 1;
    // L1: x = [frame|h0(t-1)] (fragment layout, 40 chunks); h0 -> H0f[pr] and Xb1f[nx]@171
    lstm_f<40,0><<<256,256,0,stream>>>(W1f, Xb1f + pr*XBSZ, (const u16*)nullptr,
        b1, c0, H0f[pr], 32, 0, Xb1f + nx*XBSZ, 40, 171);
    // L2: x = [h0(t) | h1(t-1)]
    lstm_f<32,32><<<256,256,0,stream>>>(W2f, H0f[pr], H1f[nx],
        b2, c1, H1f[pr], 32, 0, (u16*)nullptr, 0, 0);
    // L3: x = [h1(t) | h2(t-1)]
    lstm_f<32,32><<<256,256,0,stream>>>(W3f, H1f[pr], H2f[nx],
        b3, c2, H2f[pr], 32, 0, (u16*)nullptr, 0, 0);
    // dec: out[:,t,:] + next frame into Xb1f[nx]
    dec_f<<<11,256,0,stream>>>(Wdf, H2f[pr], bd, rseq, out, Xb1f + nx*XBSZ, cn, gn, t);
  }
}